// Round 8
// baseline (233.288 us; speedup 1.0000x reference)
//
#include <hip/hip_runtime.h>

typedef unsigned short u16;
typedef __bf16 bf16;
typedef bf16 bf16x8 __attribute__((ext_vector_type(8)));
typedef float f32x4 __attribute__((ext_vector_type(4)));
typedef u16 u16x4 __attribute__((ext_vector_type(4)));
typedef u16 u16x8 __attribute__((ext_vector_type(8)));

#define MROWS 8192      // B*S
#define EDIM 768
#define NQKV 2304       // 3*E
#define NHEAD 12
#define DH 64
#define SEQ 1024
#define BATCH 8
#define BH 96           // BATCH*NHEAD
#define BHSD (BH * SEQ * DH)
#define KIT64 (EDIM / 64)   // 12

#if __has_builtin(__builtin_amdgcn_exp2f)
#define EXP2(x) __builtin_amdgcn_exp2f(x)
#else
#define EXP2(x) exp2f(x)
#endif

// float -> bf16 (native v_cvt_pk_bf16_f32 on gfx950, RNE)
__device__ __forceinline__ u16 f2bf(float f) {
  bf16 b = (bf16)f;
  return __builtin_bit_cast(u16, b);
}

// ---------------- prep kernels ----------------

__global__ void cvt_x(const float* __restrict__ x, u16* __restrict__ xb, int n) {
  int i = (blockIdx.x * blockDim.x + threadIdx.x) * 4;
  if (i >= n) return;
  float4 v = *(const float4*)(x + i);
  u16x4 o;
  o[0] = f2bf(v.x); o[1] = f2bf(v.y); o[2] = f2bf(v.z); o[3] = f2bf(v.w);
  *(u16x4*)(xb + i) = o;
}

// LDS tile-transpose pack. Blocks 0..431: Wt tiles; 432..575: Wot tiles.
// Wt[n][e], n=region*768+h*64+d, equals W_region[h][e][d]. Wot[n][e]=Wo[e][n].
__global__ __launch_bounds__(256) void pack_w(
    const float* __restrict__ Wq, const float* __restrict__ Wk,
    const float* __restrict__ Wv, const float* __restrict__ Wo,
    u16* __restrict__ Wt, u16* __restrict__ Wot) {
  __shared__ float T[64][65];
  int bid = blockIdx.x;
  int tid = threadIdx.x;
  int c = tid & 63, r4 = tid >> 6;    // 4 rows per pass, 16 passes
  if (bid < 432) {
    int region = bid / 144, rem = bid - region * 144;
    int h = rem / 12, e0 = (rem - h * 12) * 64;
    const float* W = region == 0 ? Wq : (region == 1 ? Wk : Wv);
    for (int p = 0; p < 16; p++) {
      int er = r4 + p * 4;
      T[er][c] = W[(size_t)(h * EDIM + e0 + er) * DH + c];   // coalesced read (d=c)
    }
    __syncthreads();
    int nbase = region * EDIM + h * 64;
    for (int p = 0; p < 16; p++) {
      int dr = r4 + p * 4;
      Wt[(size_t)(nbase + dr) * EDIM + e0 + c] = f2bf(T[c][dr]);  // coalesced write (e=c)
    }
  } else {
    bid -= 432;
    int n0 = (bid / 12) * 64, e0 = (bid - (bid / 12) * 12) * 64;
    for (int p = 0; p < 16; p++) {
      int er = r4 + p * 4;
      T[er][c] = Wo[(size_t)(e0 + er) * EDIM + n0 + c];      // coalesced read (n=c)
    }
    __syncthreads();
    for (int p = 0; p < 16; p++) {
      int dr = r4 + p * 4;
      Wot[(size_t)(n0 + dr) * EDIM + e0 + c] = f2bf(T[c][dr]);
    }
  }
}

// ---------------- GEMM core: 128x128 tile, BK=64, register roundtrip ----------------
// Single LDS buffer, 2 barriers per k-iter, 12 iters. Software prefetch:
// next iter's global loads are issued after the 2nd barrier so their ~200cyc
// L2 latency overlaps the ds_read + 32-MFMA body.
// XOR swizzle (zero bank conflicts): element [row][c*8+j] stored at
// row*64 + ((c ^ (row&7))*8 + j); both writes and reads apply it.
__device__ __forceinline__ void gemm_core64(
    const u16* __restrict__ A, const u16* __restrict__ Bt,
    u16* As, u16* Bs,                 // each 128*64 elements (16 KB)
    int m0, int n0, int tid, f32x4 acc[4][4]) {
  int wv = __builtin_amdgcn_readfirstlane(tid >> 6);
  int lane = tid & 63, quad = lane >> 4, l16 = lane & 15;
  int wm = (wv & 1) * 64, wn = (wv >> 1) * 64;
  int srow = tid >> 1;              // staging row 0..127
  int cb = (tid & 1) * 4;           // chunk base 0 or 4
  const u16* Ag = A + (size_t)(m0 + srow) * EDIM + cb * 8;
  const u16* Bg = Bt + (size_t)(n0 + srow) * EDIM + cb * 8;
  int wbase = srow * 64;

  u16x8 ra[4], rb[4];
  for (int q = 0; q < 4; q++) {
    ra[q] = *(const u16x8*)(Ag + q * 8);
    rb[q] = *(const u16x8*)(Bg + q * 8);
  }
  for (int k = 0; k < KIT64; k++) {
    __syncthreads();   // previous iter's ds_reads complete before overwrite
    for (int q = 0; q < 4; q++) {
      int sc = (((cb + q) ^ (srow & 7))) * 8;
      *(u16x8*)(As + wbase + sc) = ra[q];
      *(u16x8*)(Bs + wbase + sc) = rb[q];
    }
    __syncthreads();
    if (k + 1 < KIT64) {           // prefetch next tile during compute
      int ko = (k + 1) * 64;
      for (int q = 0; q < 4; q++) {
        ra[q] = *(const u16x8*)(Ag + ko + q * 8);
        rb[q] = *(const u16x8*)(Bg + ko + q * 8);
      }
    }
    for (int kh = 0; kh < 2; kh++) {
      bf16x8 af[4], bfr[4];
      for (int i = 0; i < 4; i++) {
        int row = wm + i * 16 + l16;
        af[i] = *(const bf16x8*)(As + row * 64 + (((kh * 4 + quad) ^ (row & 7))) * 8);
      }
      for (int j = 0; j < 4; j++) {
        int row = wn + j * 16 + l16;
        bfr[j] = *(const bf16x8*)(Bs + row * 64 + (((kh * 4 + quad) ^ (row & 7))) * 8);
      }
      for (int i = 0; i < 4; i++)
        for (int j = 0; j < 4; j++)
          acc[i][j] = __builtin_amdgcn_mfma_f32_16x16x32_bf16(af[i], bfr[j], acc[i][j], 0, 0, 0);
    }
  }
}

// ---------------- GEMM 1: QKV projection ----------------
// C[8192 x 2304]; epilogue: +bias, Q*=scale(log2 domain),
// scatter: Q -> [bh][s][d], K -> [bh][t][d], V -> TRANSPOSED [bh][d][t]
__global__ __launch_bounds__(256, 3) void gemm_qkv(
    const u16* __restrict__ A, const u16* __restrict__ Bt,
    const float* __restrict__ bq, const float* __restrict__ bk, const float* __restrict__ bv,
    u16* __restrict__ qkv) {
  __shared__ u16 As[128 * 64];
  __shared__ u16 Bs[128 * 64];
  int tid = threadIdx.x;
  int wv = tid >> 6, lane = tid & 63, quad = lane >> 4, l16 = lane & 15;
  int wm = (wv & 1) * 64, wn = (wv >> 1) * 64;
  int m0 = blockIdx.x * 128, n0 = blockIdx.y * 128;
  f32x4 acc[4][4] = {};
  gemm_core64(A, Bt, As, Bs, m0, n0, tid, acc);

  const float kQscale = 0.18033688011112042f; // (1/8) * log2(e)
  for (int i = 0; i < 4; i++) {
    int row0 = m0 + wm + i * 16 + quad * 4;
    for (int j = 0; j < 4; j++) {
      int n = n0 + wn + j * 16 + l16;
      int region = n / EDIM;
      int hd = n - region * EDIM;
      int h = hd >> 6, d = hd & 63;
      const float* bp = region == 0 ? bq : (region == 1 ? bk : bv);
      float bias = bp[hd];
      float scale = region == 0 ? kQscale : 1.0f;
      for (int r = 0; r < 4; r++) {
        int rr = row0 + r;
        int bb = rr >> 10, s = rr & 1023;
        float val = (acc[i][j][r] + bias) * scale;
        u16 bv16 = f2bf(val);
        int bhh = bb * NHEAD + h;
        if (region < 2) {
          qkv[(size_t)region * BHSD + ((size_t)bhh * SEQ + s) * DH + d] = bv16;
        } else {
          qkv[(size_t)2 * BHSD + ((size_t)bhh * DH + d) * SEQ + s] = bv16;
        }
      }
    }
  }
}

// ---------------- flash attention (no-max softmax, ones-column row sums) ----------------
// grid: (8 qtiles, 96 bh). block 256 = 4 waves, each wave 32 q-rows, t-tile 32.
// Row sums computed by MFMA against a ones-column appended to V (pseudo-d tile);
// exp2 via raw v_exp_f32; bf16 via native cvt; P row stride 36 = conflict-free writes.
__global__ __launch_bounds__(256) void attn_kernel(const u16* __restrict__ qkv, u16* __restrict__ attn) {
  int bh = blockIdx.y;
  int b = bh / NHEAD, h = bh - b * NHEAD;
  const u16* Q  = qkv + (size_t)bh * SEQ * DH;
  const u16* K  = qkv + (size_t)(BH + bh) * SEQ * DH;
  const u16* VT = qkv + (size_t)(2 * BH + bh) * SEQ * DH;  // [64][1024]
  int tid = threadIdx.x, wave = tid >> 6, lane = tid & 63, quad = lane >> 4, l16 = lane & 15;
  int q_base = blockIdx.x * 128 + wave * 32;

  __shared__ u16 Ks[32 * 72];       // [t][d], row stride 72
  __shared__ u16 Vts[80 * 72];      // [d][t]; rows 0..63 = V^T, row 64 = ones, 65..79 = 0
  __shared__ u16 Ps[4][32 * 36];    // per wave P tile [q][t], row stride 36

  // one-time init of the ones/zeros pseudo-d rows (cols 0..63 are ever read)
  for (int i = tid; i < 16 * 64; i += 256) {
    int rr = i >> 6, cc = i & 63;
    Vts[(64 + rr) * 72 + cc] = (rr == 0) ? (u16)0x3F80 : (u16)0;
  }

  bf16x8 qf[2][2];
  for (int qi = 0; qi < 2; qi++)
    for (int c = 0; c < 2; c++)
      qf[qi][c] = *(const bf16x8*)(Q + (size_t)(q_base + qi * 16 + l16) * DH + c * 32 + quad * 8);

  f32x4 o[2][4] = {};
  f32x4 o5[2] = {};   // row-sum accumulator (col 0 = sum over t)

  int tr = tid >> 3, tc8 = (tid & 7) * 8;   // K staging: 32 rows x 64 cols
  int vr = tid >> 2, vc8 = (tid & 3) * 8;   // VT staging: 64 rows x 32 cols

  for (int t0 = 0; t0 < SEQ; t0 += 32) {
    u16x8 kv = *(const u16x8*)(K + (size_t)(t0 + tr) * DH + tc8);
    u16x8 vv = *(const u16x8*)(VT + (size_t)vr * SEQ + t0 + vc8);
    __syncthreads();
    *(u16x8*)(Ks + tr * 72 + tc8) = kv;
    *(u16x8*)(Vts + vr * 72 + vc8) = vv;
    __syncthreads();

    bf16x8 kf[2][2];
    for (int tc = 0; tc < 2; tc++)
      for (int c = 0; c < 2; c++)
        kf[tc][c] = *(const bf16x8*)(Ks + (tc * 16 + l16) * 72 + c * 32 + quad * 8);

    // scores + exp2 (logits in log2 domain via Q scale; statistically bounded, no max)
    float p[2][2][4];
    for (int qi = 0; qi < 2; qi++)
      for (int tc = 0; tc < 2; tc++) {
        f32x4 z = {};
        z = __builtin_amdgcn_mfma_f32_16x16x32_bf16(qf[qi][0], kf[tc][0], z, 0, 0, 0);
        z = __builtin_amdgcn_mfma_f32_16x16x32_bf16(qf[qi][1], kf[tc][1], z, 0, 0, 0);
        for (int r = 0; r < 4; r++)
          p[qi][tc][r] = EXP2(z[r]);
      }

    // P: C-layout -> A-layout via per-wave LDS round trip (stride 36: quads on
    // disjoint bank octets, only free 2-way word sharing)
    u16* P = Ps[wave];
    for (int qi = 0; qi < 2; qi++)
      for (int tc = 0; tc < 2; tc++)
        for (int r = 0; r < 4; r++)
          P[(qi * 16 + quad * 4 + r) * 36 + tc * 16 + l16] = f2bf(p[qi][tc][r]);
    bf16x8 pf[2];
    for (int qi = 0; qi < 2; qi++)
      pf[qi] = *(const bf16x8*)(P + (qi * 16 + l16) * 36 + quad * 8);

    bf16x8 vf[4], vf5;
    for (int n = 0; n < 4; n++)
      vf[n] = *(const bf16x8*)(Vts + (n * 16 + l16) * 72 + quad * 8);
    vf5 = *(const bf16x8*)(Vts + (64 + l16) * 72 + quad * 8);

    for (int qi = 0; qi < 2; qi++) {
      for (int n = 0; n < 4; n++)
        o[qi][n] = __builtin_amdgcn_mfma_f32_16x16x32_bf16(pf[qi], vf[n], o[qi][n], 0, 0, 0);
      o5[qi] = __builtin_amdgcn_mfma_f32_16x16x32_bf16(pf[qi], vf5, o5[qi], 0, 0, 0);
    }
  }

  // normalize + store to attn [8192][768] bf16, col = h*64 + d.
  // row sum for row quad*4+r lives in lane quad*16 (col 0) of o5.
  for (int qi = 0; qi < 2; qi++)
    for (int r = 0; r < 4; r++) {
      float s = __shfl(o5[qi][r], quad << 4);
      float inv = 1.0f / s;
      int qrow = q_base + qi * 16 + quad * 4 + r;
      size_t rowoff = (size_t)(b * SEQ + qrow) * EDIM + h * DH;
      for (int n = 0; n < 4; n++)
        attn[rowoff + n * 16 + l16] = f2bf(o[qi][n][r] * inv);
    }
}

// ---------------- GEMM 3: output projection ----------------
__global__ __launch_bounds__(256, 3) void gemm_out(
    const u16* __restrict__ A, const u16* __restrict__ Bt,
    const float* __restrict__ bo, float* __restrict__ out) {
  __shared__ u16 As[128 * 64];
  __shared__ u16 Bs[128 * 64];
  int tid = threadIdx.x;
  int wv = tid >> 6, lane = tid & 63, quad = lane >> 4, l16 = lane & 15;
  int wm = (wv & 1) * 64, wn = (wv >> 1) * 64;
  int m0 = blockIdx.x * 128, n0 = blockIdx.y * 128;
  f32x4 acc[4][4] = {};
  gemm_core64(A, Bt, As, Bs, m0, n0, tid, acc);

  for (int i = 0; i < 4; i++) {
    int row0 = m0 + wm + i * 16 + quad * 4;
    for (int j = 0; j < 4; j++) {
      int n = n0 + wn + j * 16 + l16;
      float bias = bo[n];
      for (int r = 0; r < 4; r++)
        out[(size_t)(row0 + r) * EDIM + n] = acc[i][j][r] + bias;
    }
  }
}

// ---------------- launch ----------------
extern "C" void kernel_launch(void* const* d_in, const int* in_sizes, int n_in,
                              void* d_out, int out_size, void* d_ws, size_t ws_size,
                              hipStream_t stream) {
  const float* x  = (const float*)d_in[0];
  const float* Wq = (const float*)d_in[1];
  const float* bq = (const float*)d_in[2];
  const float* Wk = (const float*)d_in[3];
  const float* bk = (const float*)d_in[4];
  const float* Wv = (const float*)d_in[5];
  const float* bv = (const float*)d_in[6];
  const float* Wo = (const float*)d_in[7];
  const float* bo = (const float*)d_in[8];
  float* out = (float*)d_out;
  char* ws = (char*)d_ws;

  u16* Xb   = (u16*)(ws);                      // 8192*768*2    = 12,582,912
  u16* Wt   = (u16*)(ws + 12582912);           // 2304*768*2    =  3,538,944
  u16* Wot  = (u16*)(ws + 16121856);           // 768*768*2     =  1,179,648
  u16* qkv  = (u16*)(ws + 17301504);           // 3*96*1024*64*2= 37,748,736
  u16* attn = (u16*)(ws + 55050240);           // 8192*768*2    = 12,582,912

  cvt_x<<<6144, 256, 0, stream>>>(x, Xb, MROWS * EDIM);
  pack_w<<<576, 256, 0, stream>>>(Wq, Wk, Wv, Wo, Wt, Wot);
  gemm_qkv<<<dim3(64, 18), 256, 0, stream>>>(Xb, Wt, bq, bk, bv, qkv);
  attn_kernel<<<dim3(8, 96), 256, 0, stream>>>(qkv, attn);
  gemm_out<<<dim3(64, 6), 256, 0, stream>>>(attn, Wot, bo, out);
}

// Round 9
// 225.257 us; speedup vs baseline: 1.0357x; 1.0357x over previous
//
#include <hip/hip_runtime.h>

typedef unsigned short u16;
typedef __bf16 bf16;
typedef bf16 bf16x8 __attribute__((ext_vector_type(8)));
typedef float f32x4 __attribute__((ext_vector_type(4)));
typedef u16 u16x4 __attribute__((ext_vector_type(4)));
typedef u16 u16x8 __attribute__((ext_vector_type(8)));

#define MROWS 8192      // B*S
#define EDIM 768
#define NQKV 2304       // 3*E
#define NHEAD 12
#define DH 64
#define SEQ 1024
#define BATCH 8
#define BH 96           // BATCH*NHEAD
#define BHSD (BH * SEQ * DH)
#define KIT64 (EDIM / 64)   // 12

#if __has_builtin(__builtin_amdgcn_exp2f)
#define EXP2(x) __builtin_amdgcn_exp2f(x)
#else
#define EXP2(x) exp2f(x)
#endif

// float -> bf16 (native v_cvt_pk_bf16_f32 on gfx950, RNE)
__device__ __forceinline__ u16 f2bf(float f) {
  bf16 b = (bf16)f;
  return __builtin_bit_cast(u16, b);
}

// ---------------- prep kernels ----------------

__global__ void cvt_x(const float* __restrict__ x, u16* __restrict__ xb, int n) {
  int i = (blockIdx.x * blockDim.x + threadIdx.x) * 4;
  if (i >= n) return;
  float4 v = *(const float4*)(x + i);
  u16x4 o;
  o[0] = f2bf(v.x); o[1] = f2bf(v.y); o[2] = f2bf(v.z); o[3] = f2bf(v.w);
  *(u16x4*)(xb + i) = o;
}

// LDS tile-transpose pack. Blocks 0..431: Wt tiles; 432..575: Wot tiles.
// Wt[n][e], n=region*768+h*64+d, equals W_region[h][e][d]. Wot[n][e]=Wo[e][n].
__global__ __launch_bounds__(256) void pack_w(
    const float* __restrict__ Wq, const float* __restrict__ Wk,
    const float* __restrict__ Wv, const float* __restrict__ Wo,
    u16* __restrict__ Wt, u16* __restrict__ Wot) {
  __shared__ float T[64][65];
  int bid = blockIdx.x;
  int tid = threadIdx.x;
  int c = tid & 63, r4 = tid >> 6;    // 4 rows per pass, 16 passes
  if (bid < 432) {
    int region = bid / 144, rem = bid - region * 144;
    int h = rem / 12, e0 = (rem - h * 12) * 64;
    const float* W = region == 0 ? Wq : (region == 1 ? Wk : Wv);
    for (int p = 0; p < 16; p++) {
      int er = r4 + p * 4;
      T[er][c] = W[(size_t)(h * EDIM + e0 + er) * DH + c];   // coalesced read (d=c)
    }
    __syncthreads();
    int nbase = region * EDIM + h * 64;
    for (int p = 0; p < 16; p++) {
      int dr = r4 + p * 4;
      Wt[(size_t)(nbase + dr) * EDIM + e0 + c] = f2bf(T[c][dr]);  // coalesced write (e=c)
    }
  } else {
    bid -= 432;
    int n0 = (bid / 12) * 64, e0 = (bid - (bid / 12) * 12) * 64;
    for (int p = 0; p < 16; p++) {
      int er = r4 + p * 4;
      T[er][c] = Wo[(size_t)(e0 + er) * EDIM + n0 + c];      // coalesced read (n=c)
    }
    __syncthreads();
    for (int p = 0; p < 16; p++) {
      int dr = r4 + p * 4;
      Wot[(size_t)(n0 + dr) * EDIM + e0 + c] = f2bf(T[c][dr]);
    }
  }
}

// ---------------- GEMM core: 128x128 tile, BK=64, register roundtrip ----------------
// Single LDS buffer, 2 barriers per k-iter, 12 iters. Software prefetch:
// next iter's global loads are issued after the 2nd barrier so their ~200cyc
// L2 latency overlaps the ds_read + 32-MFMA body.
// XOR swizzle (zero bank conflicts): element [row][c*8+j] stored at
// row*64 + ((c ^ (row&7))*8 + j); both writes and reads apply it.
__device__ __forceinline__ void gemm_core64(
    const u16* __restrict__ A, const u16* __restrict__ Bt,
    u16* As, u16* Bs,                 // each 128*64 elements (16 KB)
    int m0, int n0, int tid, f32x4 acc[4][4]) {
  int wv = __builtin_amdgcn_readfirstlane(tid >> 6);
  int lane = tid & 63, quad = lane >> 4, l16 = lane & 15;
  int wm = (wv & 1) * 64, wn = (wv >> 1) * 64;
  int srow = tid >> 1;              // staging row 0..127
  int cb = (tid & 1) * 4;           // chunk base 0 or 4
  const u16* Ag = A + (size_t)(m0 + srow) * EDIM + cb * 8;
  const u16* Bg = Bt + (size_t)(n0 + srow) * EDIM + cb * 8;
  int wbase = srow * 64;

  u16x8 ra[4], rb[4];
  for (int q = 0; q < 4; q++) {
    ra[q] = *(const u16x8*)(Ag + q * 8);
    rb[q] = *(const u16x8*)(Bg + q * 8);
  }
  for (int k = 0; k < KIT64; k++) {
    __syncthreads();   // previous iter's ds_reads complete before overwrite
    for (int q = 0; q < 4; q++) {
      int sc = (((cb + q) ^ (srow & 7))) * 8;
      *(u16x8*)(As + wbase + sc) = ra[q];
      *(u16x8*)(Bs + wbase + sc) = rb[q];
    }
    __syncthreads();
    if (k + 1 < KIT64) {           // prefetch next tile during compute
      int ko = (k + 1) * 64;
      for (int q = 0; q < 4; q++) {
        ra[q] = *(const u16x8*)(Ag + ko + q * 8);
        rb[q] = *(const u16x8*)(Bg + ko + q * 8);
      }
    }
    for (int kh = 0; kh < 2; kh++) {
      bf16x8 af[4], bfr[4];
      for (int i = 0; i < 4; i++) {
        int row = wm + i * 16 + l16;
        af[i] = *(const bf16x8*)(As + row * 64 + (((kh * 4 + quad) ^ (row & 7))) * 8);
      }
      for (int j = 0; j < 4; j++) {
        int row = wn + j * 16 + l16;
        bfr[j] = *(const bf16x8*)(Bs + row * 64 + (((kh * 4 + quad) ^ (row & 7))) * 8);
      }
      for (int i = 0; i < 4; i++)
        for (int j = 0; j < 4; j++)
          acc[i][j] = __builtin_amdgcn_mfma_f32_16x16x32_bf16(af[i], bfr[j], acc[i][j], 0, 0, 0);
    }
  }
}

// ---------------- GEMM 1: QKV projection ----------------
// C[8192 x 2304]; epilogue: +bias, Q*=scale(log2 domain),
// scatter: Q -> [bh][s][d], K -> [bh][t][d], V -> TRANSPOSED [bh][d][t]
__global__ __launch_bounds__(256, 3) void gemm_qkv(
    const u16* __restrict__ A, const u16* __restrict__ Bt,
    const float* __restrict__ bq, const float* __restrict__ bk, const float* __restrict__ bv,
    u16* __restrict__ qkv) {
  __shared__ u16 As[128 * 64];
  __shared__ u16 Bs[128 * 64];
  int tid = threadIdx.x;
  int wv = tid >> 6, lane = tid & 63, quad = lane >> 4, l16 = lane & 15;
  int wm = (wv & 1) * 64, wn = (wv >> 1) * 64;
  int m0 = blockIdx.x * 128, n0 = blockIdx.y * 128;
  f32x4 acc[4][4] = {};
  gemm_core64(A, Bt, As, Bs, m0, n0, tid, acc);

  const float kQscale = 0.18033688011112042f; // (1/8) * log2(e)
  for (int i = 0; i < 4; i++) {
    int row0 = m0 + wm + i * 16 + quad * 4;
    for (int j = 0; j < 4; j++) {
      int n = n0 + wn + j * 16 + l16;
      int region = n / EDIM;
      int hd = n - region * EDIM;
      int h = hd >> 6, d = hd & 63;
      const float* bp = region == 0 ? bq : (region == 1 ? bk : bv);
      float bias = bp[hd];
      float scale = region == 0 ? kQscale : 1.0f;
      for (int r = 0; r < 4; r++) {
        int rr = row0 + r;
        int bb = rr >> 10, s = rr & 1023;
        float val = (acc[i][j][r] + bias) * scale;
        u16 bv16 = f2bf(val);
        int bhh = bb * NHEAD + h;
        if (region < 2) {
          qkv[(size_t)region * BHSD + ((size_t)bhh * SEQ + s) * DH + d] = bv16;
        } else {
          qkv[(size_t)2 * BHSD + ((size_t)bhh * DH + d) * SEQ + s] = bv16;
        }
      }
    }
  }
}

// ---------------- flash attention (no-max softmax, ones-column row sums) ----------------
// grid: (96 bh, 8 qtiles) => XCD = bh%8: all q-tile blocks of a bh share one
// XCD's L2 copy of K/V. Register-roundtrip prefetch: next K/V tile's global
// loads issue after the 2nd barrier, overlapping the MFMA/softmax body.
__global__ __launch_bounds__(256) void attn_kernel(const u16* __restrict__ qkv, u16* __restrict__ attn) {
  int bh = blockIdx.x;
  int b = bh / NHEAD, h = bh - b * NHEAD;
  const u16* Q  = qkv + (size_t)bh * SEQ * DH;
  const u16* K  = qkv + (size_t)(BH + bh) * SEQ * DH;
  const u16* VT = qkv + (size_t)(2 * BH + bh) * SEQ * DH;  // [64][1024]
  int tid = threadIdx.x, wave = tid >> 6, lane = tid & 63, quad = lane >> 4, l16 = lane & 15;
  int q_base = blockIdx.y * 128 + wave * 32;

  __shared__ u16 Ks[32 * 72];       // [t][d], row stride 72
  __shared__ u16 Vts[80 * 72];      // [d][t]; rows 0..63 = V^T, row 64 = ones, 65..79 = 0
  __shared__ u16 Ps[4][32 * 36];    // per wave P tile [q][t], row stride 36

  // one-time init of the ones/zeros pseudo-d rows (cols 0..63 are ever read)
  for (int i = tid; i < 16 * 64; i += 256) {
    int rr = i >> 6, cc = i & 63;
    Vts[(64 + rr) * 72 + cc] = (rr == 0) ? (u16)0x3F80 : (u16)0;
  }

  bf16x8 qf[2][2];
  for (int qi = 0; qi < 2; qi++)
    for (int c = 0; c < 2; c++)
      qf[qi][c] = *(const bf16x8*)(Q + (size_t)(q_base + qi * 16 + l16) * DH + c * 32 + quad * 8);

  f32x4 o[2][4] = {};
  f32x4 o5[2] = {};   // row-sum accumulator (col 0 = sum over t)

  int tr = tid >> 3, tc8 = (tid & 7) * 8;   // K staging: 32 rows x 64 cols
  int vr = tid >> 2, vc8 = (tid & 3) * 8;   // VT staging: 64 rows x 32 cols

  // prologue: prefetch tile 0 into registers
  u16x8 kv = *(const u16x8*)(K + (size_t)tr * DH + tc8);
  u16x8 vv = *(const u16x8*)(VT + (size_t)vr * SEQ + vc8);

  for (int t0 = 0; t0 < SEQ; t0 += 32) {
    __syncthreads();
    *(u16x8*)(Ks + tr * 72 + tc8) = kv;
    *(u16x8*)(Vts + vr * 72 + vc8) = vv;
    __syncthreads();
    if (t0 + 32 < SEQ) {   // prefetch next tile during compute
      kv = *(const u16x8*)(K + (size_t)(t0 + 32 + tr) * DH + tc8);
      vv = *(const u16x8*)(VT + (size_t)vr * SEQ + t0 + 32 + vc8);
    }

    bf16x8 kf[2][2];
    for (int tc = 0; tc < 2; tc++)
      for (int c = 0; c < 2; c++)
        kf[tc][c] = *(const bf16x8*)(Ks + (tc * 16 + l16) * 72 + c * 32 + quad * 8);

    // scores + exp2 (logits in log2 domain via Q scale; statistically bounded, no max)
    float p[2][2][4];
    for (int qi = 0; qi < 2; qi++)
      for (int tc = 0; tc < 2; tc++) {
        f32x4 z = {};
        z = __builtin_amdgcn_mfma_f32_16x16x32_bf16(qf[qi][0], kf[tc][0], z, 0, 0, 0);
        z = __builtin_amdgcn_mfma_f32_16x16x32_bf16(qf[qi][1], kf[tc][1], z, 0, 0, 0);
        for (int r = 0; r < 4; r++)
          p[qi][tc][r] = EXP2(z[r]);
      }

    // P: C-layout -> A-layout via per-wave LDS round trip (stride 36: quads on
    // disjoint bank octets, only free 2-way word sharing)
    u16* P = Ps[wave];
    for (int qi = 0; qi < 2; qi++)
      for (int tc = 0; tc < 2; tc++)
        for (int r = 0; r < 4; r++)
          P[(qi * 16 + quad * 4 + r) * 36 + tc * 16 + l16] = f2bf(p[qi][tc][r]);
    bf16x8 pf[2];
    for (int qi = 0; qi < 2; qi++)
      pf[qi] = *(const bf16x8*)(P + (qi * 16 + l16) * 36 + quad * 8);

    bf16x8 vf[4], vf5;
    for (int n = 0; n < 4; n++)
      vf[n] = *(const bf16x8*)(Vts + (n * 16 + l16) * 72 + quad * 8);
    vf5 = *(const bf16x8*)(Vts + (64 + l16) * 72 + quad * 8);

    for (int qi = 0; qi < 2; qi++) {
      for (int n = 0; n < 4; n++)
        o[qi][n] = __builtin_amdgcn_mfma_f32_16x16x32_bf16(pf[qi], vf[n], o[qi][n], 0, 0, 0);
      o5[qi] = __builtin_amdgcn_mfma_f32_16x16x32_bf16(pf[qi], vf5, o5[qi], 0, 0, 0);
    }
  }

  // normalize + store to attn [8192][768] bf16, col = h*64 + d.
  // row sum for row quad*4+r lives in lane quad*16 (col 0) of o5.
  for (int qi = 0; qi < 2; qi++)
    for (int r = 0; r < 4; r++) {
      float s = __shfl(o5[qi][r], quad << 4);
      float inv = 1.0f / s;
      int qrow = q_base + qi * 16 + quad * 4 + r;
      size_t rowoff = (size_t)(b * SEQ + qrow) * EDIM + h * DH;
      for (int n = 0; n < 4; n++)
        attn[rowoff + n * 16 + l16] = f2bf(o[qi][n][r] * inv);
    }
}

// ---------------- GEMM 3: output projection ----------------
__global__ __launch_bounds__(256, 3) void gemm_out(
    const u16* __restrict__ A, const u16* __restrict__ Bt,
    const float* __restrict__ bo, float* __restrict__ out) {
  __shared__ u16 As[128 * 64];
  __shared__ u16 Bs[128 * 64];
  int tid = threadIdx.x;
  int wv = tid >> 6, lane = tid & 63, quad = lane >> 4, l16 = lane & 15;
  int wm = (wv & 1) * 64, wn = (wv >> 1) * 64;
  int m0 = blockIdx.x * 128, n0 = blockIdx.y * 128;
  f32x4 acc[4][4] = {};
  gemm_core64(A, Bt, As, Bs, m0, n0, tid, acc);

  for (int i = 0; i < 4; i++) {
    int row0 = m0 + wm + i * 16 + quad * 4;
    for (int j = 0; j < 4; j++) {
      int n = n0 + wn + j * 16 + l16;
      float bias = bo[n];
      for (int r = 0; r < 4; r++)
        out[(size_t)(row0 + r) * EDIM + n] = acc[i][j][r] + bias;
    }
  }
}

// ---------------- launch ----------------
extern "C" void kernel_launch(void* const* d_in, const int* in_sizes, int n_in,
                              void* d_out, int out_size, void* d_ws, size_t ws_size,
                              hipStream_t stream) {
  const float* x  = (const float*)d_in[0];
  const float* Wq = (const float*)d_in[1];
  const float* bq = (const float*)d_in[2];
  const float* Wk = (const float*)d_in[3];
  const float* bk = (const float*)d_in[4];
  const float* Wv = (const float*)d_in[5];
  const float* bv = (const float*)d_in[6];
  const float* Wo = (const float*)d_in[7];
  const float* bo = (const float*)d_in[8];
  float* out = (float*)d_out;
  char* ws = (char*)d_ws;

  u16* Xb   = (u16*)(ws);                      // 8192*768*2    = 12,582,912
  u16* Wt   = (u16*)(ws + 12582912);           // 2304*768*2    =  3,538,944
  u16* Wot  = (u16*)(ws + 16121856);           // 768*768*2     =  1,179,648
  u16* qkv  = (u16*)(ws + 17301504);           // 3*96*1024*64*2= 37,748,736
  u16* attn = (u16*)(ws + 55050240);           // 8192*768*2    = 12,582,912

  cvt_x<<<6144, 256, 0, stream>>>(x, Xb, MROWS * EDIM);
  pack_w<<<576, 256, 0, stream>>>(Wq, Wk, Wv, Wo, Wt, Wot);
  gemm_qkv<<<dim3(64, 18), 256, 0, stream>>>(Xb, Wt, bq, bk, bv, qkv);
  attn_kernel<<<dim3(96, 8), 256, 0, stream>>>(qkv, attn);
  gemm_out<<<dim3(64, 6), 256, 0, stream>>>(attn, Wot, bo, out);
}

// Round 10
// 216.700 us; speedup vs baseline: 1.0765x; 1.0395x over previous
//
#include <hip/hip_runtime.h>

typedef unsigned short u16;
typedef __bf16 bf16;
typedef bf16 bf16x8 __attribute__((ext_vector_type(8)));
typedef float f32x4 __attribute__((ext_vector_type(4)));
typedef u16 u16x4 __attribute__((ext_vector_type(4)));
typedef u16 u16x8 __attribute__((ext_vector_type(8)));

#define MROWS 8192      // B*S
#define EDIM 768
#define NQKV 2304       // 3*E
#define NHEAD 12
#define DH 64
#define SEQ 1024
#define BATCH 8
#define BH 96           // BATCH*NHEAD
#define BHSD (BH * SEQ * DH)
#define KIT64 (EDIM / 64)   // 12

#if __has_builtin(__builtin_amdgcn_exp2f)
#define EXP2(x) __builtin_amdgcn_exp2f(x)
#else
#define EXP2(x) exp2f(x)
#endif

// float -> bf16 (native cvt on gfx950, RNE)
__device__ __forceinline__ u16 f2bf(float f) {
  bf16 b = (bf16)f;
  return __builtin_bit_cast(u16, b);
}

// ---------------- prep kernels ----------------

__global__ void cvt_x(const float* __restrict__ x, u16* __restrict__ xb, int n) {
  int i = (blockIdx.x * blockDim.x + threadIdx.x) * 4;
  if (i >= n) return;
  float4 v = *(const float4*)(x + i);
  u16x4 o;
  o[0] = f2bf(v.x); o[1] = f2bf(v.y); o[2] = f2bf(v.z); o[3] = f2bf(v.w);
  *(u16x4*)(xb + i) = o;
}

// LDS tile-transpose pack. Blocks 0..431: Wt tiles; 432..575: Wot tiles.
// Wt[n][e], n=region*768+h*64+d, equals W_region[h][e][d]. Wot[n][e]=Wo[e][n].
__global__ __launch_bounds__(256) void pack_w(
    const float* __restrict__ Wq, const float* __restrict__ Wk,
    const float* __restrict__ Wv, const float* __restrict__ Wo,
    u16* __restrict__ Wt, u16* __restrict__ Wot) {
  __shared__ float T[64][65];
  int bid = blockIdx.x;
  int tid = threadIdx.x;
  int c = tid & 63, r4 = tid >> 6;    // 4 rows per pass, 16 passes
  if (bid < 432) {
    int region = bid / 144, rem = bid - region * 144;
    int h = rem / 12, e0 = (rem - h * 12) * 64;
    const float* W = region == 0 ? Wq : (region == 1 ? Wk : Wv);
    for (int p = 0; p < 16; p++) {
      int er = r4 + p * 4;
      T[er][c] = W[(size_t)(h * EDIM + e0 + er) * DH + c];   // coalesced read (d=c)
    }
    __syncthreads();
    int nbase = region * EDIM + h * 64;
    for (int p = 0; p < 16; p++) {
      int dr = r4 + p * 4;
      Wt[(size_t)(nbase + dr) * EDIM + e0 + c] = f2bf(T[c][dr]);  // coalesced write (e=c)
    }
  } else {
    bid -= 432;
    int n0 = (bid / 12) * 64, e0 = (bid - (bid / 12) * 12) * 64;
    for (int p = 0; p < 16; p++) {
      int er = r4 + p * 4;
      T[er][c] = Wo[(size_t)(e0 + er) * EDIM + n0 + c];      // coalesced read (n=c)
    }
    __syncthreads();
    for (int p = 0; p < 16; p++) {
      int dr = r4 + p * 4;
      Wot[(size_t)(n0 + dr) * EDIM + e0 + c] = f2bf(T[c][dr]);
    }
  }
}

// ---------------- GEMM core: 128x128 tile, BK=64, register roundtrip ----------------
// Single LDS buffer, 2 barriers per k-iter, 12 iters. Software prefetch:
// next iter's global loads are issued after the 2nd barrier so their ~200cyc
// L2 latency overlaps the ds_read + 32-MFMA body.
// XOR swizzle (zero bank conflicts): element [row][c*8+j] stored at
// row*64 + ((c ^ (row&7))*8 + j); both writes and reads apply it.
__device__ __forceinline__ void gemm_core64(
    const u16* __restrict__ A, const u16* __restrict__ Bt,
    u16* As, u16* Bs,                 // each 128*64 elements (16 KB)
    int m0, int n0, int tid, f32x4 acc[4][4]) {
  int wv = __builtin_amdgcn_readfirstlane(tid >> 6);
  int lane = tid & 63, quad = lane >> 4, l16 = lane & 15;
  int wm = (wv & 1) * 64, wn = (wv >> 1) * 64;
  int srow = tid >> 1;              // staging row 0..127
  int cb = (tid & 1) * 4;           // chunk base 0 or 4
  const u16* Ag = A + (size_t)(m0 + srow) * EDIM + cb * 8;
  const u16* Bg = Bt + (size_t)(n0 + srow) * EDIM + cb * 8;
  int wbase = srow * 64;

  u16x8 ra[4], rb[4];
  for (int q = 0; q < 4; q++) {
    ra[q] = *(const u16x8*)(Ag + q * 8);
    rb[q] = *(const u16x8*)(Bg + q * 8);
  }
  for (int k = 0; k < KIT64; k++) {
    __syncthreads();   // previous iter's ds_reads complete before overwrite
    for (int q = 0; q < 4; q++) {
      int sc = (((cb + q) ^ (srow & 7))) * 8;
      *(u16x8*)(As + wbase + sc) = ra[q];
      *(u16x8*)(Bs + wbase + sc) = rb[q];
    }
    __syncthreads();
    if (k + 1 < KIT64) {           // prefetch next tile during compute
      int ko = (k + 1) * 64;
      for (int q = 0; q < 4; q++) {
        ra[q] = *(const u16x8*)(Ag + ko + q * 8);
        rb[q] = *(const u16x8*)(Bg + ko + q * 8);
      }
    }
    for (int kh = 0; kh < 2; kh++) {
      bf16x8 af[4], bfr[4];
      for (int i = 0; i < 4; i++) {
        int row = wm + i * 16 + l16;
        af[i] = *(const bf16x8*)(As + row * 64 + (((kh * 4 + quad) ^ (row & 7))) * 8);
      }
      for (int j = 0; j < 4; j++) {
        int row = wn + j * 16 + l16;
        bfr[j] = *(const bf16x8*)(Bs + row * 64 + (((kh * 4 + quad) ^ (row & 7))) * 8);
      }
      for (int i = 0; i < 4; i++)
        for (int j = 0; j < 4; j++)
          acc[i][j] = __builtin_amdgcn_mfma_f32_16x16x32_bf16(af[i], bfr[j], acc[i][j], 0, 0, 0);
    }
  }
}

// ---------------- GEMM 1: QKV projection ----------------
// C[8192 x 2304]; epilogue: +bias, Q*=scale(log2 domain),
// scatter: Q -> [bh][s][d], K -> [bh][t][d], V -> TRANSPOSED [bh][d][t]
__global__ __launch_bounds__(256, 3) void gemm_qkv(
    const u16* __restrict__ A, const u16* __restrict__ Bt,
    const float* __restrict__ bq, const float* __restrict__ bk, const float* __restrict__ bv,
    u16* __restrict__ qkv) {
  __shared__ u16 As[128 * 64];
  __shared__ u16 Bs[128 * 64];
  int tid = threadIdx.x;
  int wv = tid >> 6, lane = tid & 63, quad = lane >> 4, l16 = lane & 15;
  int wm = (wv & 1) * 64, wn = (wv >> 1) * 64;
  int m0 = blockIdx.x * 128, n0 = blockIdx.y * 128;
  f32x4 acc[4][4] = {};
  gemm_core64(A, Bt, As, Bs, m0, n0, tid, acc);

  const float kQscale = 0.18033688011112042f; // (1/8) * log2(e)
  for (int i = 0; i < 4; i++) {
    int row0 = m0 + wm + i * 16 + quad * 4;
    for (int j = 0; j < 4; j++) {
      int n = n0 + wn + j * 16 + l16;
      int region = n / EDIM;
      int hd = n - region * EDIM;
      int h = hd >> 6, d = hd & 63;
      const float* bp = region == 0 ? bq : (region == 1 ? bk : bv);
      float bias = bp[hd];
      float scale = region == 0 ? kQscale : 1.0f;
      for (int r = 0; r < 4; r++) {
        int rr = row0 + r;
        int bb = rr >> 10, s = rr & 1023;
        float val = (acc[i][j][r] + bias) * scale;
        u16 bv16 = f2bf(val);
        int bhh = bb * NHEAD + h;
        if (region < 2) {
          qkv[(size_t)region * BHSD + ((size_t)bhh * SEQ + s) * DH + d] = bv16;
        } else {
          qkv[(size_t)2 * BHSD + ((size_t)bhh * DH + d) * SEQ + s] = bv16;
        }
      }
    }
  }
}

// ---------------- flash attention (no-max softmax, ones-column row sums) ----------------
// grid (96 bh, 16 qtiles): XCD = bh%8 keeps K/V L2-local; 1536 blocks give
// ~4-5 resident blocks/CU of independent barrier streams. Each wave owns 16
// q-rows; t-tile 64 halves barrier count per unit work. Register-roundtrip
// prefetch of next K/V tile overlaps the MFMA/softmax body.
__global__ __launch_bounds__(256, 4) void attn_kernel(const u16* __restrict__ qkv, u16* __restrict__ attn) {
  int bh = blockIdx.x;
  int b = bh / NHEAD, h = bh - b * NHEAD;
  const u16* Q  = qkv + (size_t)bh * SEQ * DH;
  const u16* K  = qkv + (size_t)(BH + bh) * SEQ * DH;
  const u16* VT = qkv + (size_t)(2 * BH + bh) * SEQ * DH;  // [64][1024]
  int tid = threadIdx.x, wave = tid >> 6, lane = tid & 63, quad = lane >> 4, l16 = lane & 15;
  int q_base = blockIdx.y * 64 + wave * 16;

  __shared__ u16 Ks[64 * 72];       // [t][d], row stride 72
  __shared__ u16 Vts[80 * 72];      // [d][t]; rows 0..63 = V^T, row 64 = ones, 65..79 = 0
  __shared__ u16 Ps[4][16 * 72];    // per wave P tile [q][t], row stride 72

  // one-time init of the ones/zeros pseudo-d rows (cols 0..63 ever read)
  for (int i = tid; i < 16 * 64; i += 256) {
    int rr = i >> 6, cc = i & 63;
    Vts[(64 + rr) * 72 + cc] = (rr == 0) ? (u16)0x3F80 : (u16)0;
  }

  bf16x8 qf[2];
  for (int c = 0; c < 2; c++)
    qf[c] = *(const bf16x8*)(Q + (size_t)(q_base + l16) * DH + c * 32 + quad * 8);

  f32x4 o[4] = {};
  f32x4 o5 = {};   // row-sum accumulator (col 0 = sum over t)

  int tr = tid >> 3, tc8 = (tid & 7) * 8;   // staging: rows 0..31 (+32), 8 col-chunks

  // prologue: prefetch tile 0 into registers
  u16x8 kv0 = *(const u16x8*)(K + (size_t)tr * DH + tc8);
  u16x8 kv1 = *(const u16x8*)(K + (size_t)(32 + tr) * DH + tc8);
  u16x8 vv0 = *(const u16x8*)(VT + (size_t)tr * SEQ + tc8);
  u16x8 vv1 = *(const u16x8*)(VT + (size_t)(32 + tr) * SEQ + tc8);

  for (int t0 = 0; t0 < SEQ; t0 += 64) {
    __syncthreads();
    *(u16x8*)(Ks + tr * 72 + tc8) = kv0;
    *(u16x8*)(Ks + (tr + 32) * 72 + tc8) = kv1;
    *(u16x8*)(Vts + tr * 72 + tc8) = vv0;
    *(u16x8*)(Vts + (tr + 32) * 72 + tc8) = vv1;
    __syncthreads();
    if (t0 + 64 < SEQ) {   // prefetch next tile during compute
      kv0 = *(const u16x8*)(K + (size_t)(t0 + 64 + tr) * DH + tc8);
      kv1 = *(const u16x8*)(K + (size_t)(t0 + 96 + tr) * DH + tc8);
      vv0 = *(const u16x8*)(VT + (size_t)tr * SEQ + t0 + 64 + tc8);
      vv1 = *(const u16x8*)(VT + (size_t)(32 + tr) * SEQ + t0 + 64 + tc8);
    }

    // scores + exp2 (logits in log2 domain via Q scale; statistically bounded, no max)
    float p[4][4];
    for (int tc = 0; tc < 4; tc++) {
      bf16x8 kf0 = *(const bf16x8*)(Ks + (tc * 16 + l16) * 72 + quad * 8);
      bf16x8 kf1 = *(const bf16x8*)(Ks + (tc * 16 + l16) * 72 + 32 + quad * 8);
      f32x4 z = {};
      z = __builtin_amdgcn_mfma_f32_16x16x32_bf16(qf[0], kf0, z, 0, 0, 0);
      z = __builtin_amdgcn_mfma_f32_16x16x32_bf16(qf[1], kf1, z, 0, 0, 0);
      for (int r = 0; r < 4; r++)
        p[tc][r] = EXP2(z[r]);
    }

    // P: C-layout -> A-layout via per-wave LDS round trip
    u16* P = Ps[wave];
    for (int tc = 0; tc < 4; tc++)
      for (int r = 0; r < 4; r++)
        P[(quad * 4 + r) * 72 + tc * 16 + l16] = f2bf(p[tc][r]);
    bf16x8 pf[2];
    for (int kc = 0; kc < 2; kc++)
      pf[kc] = *(const bf16x8*)(P + l16 * 72 + kc * 32 + quad * 8);

    for (int n = 0; n < 4; n++) {
      bf16x8 vf0 = *(const bf16x8*)(Vts + (n * 16 + l16) * 72 + quad * 8);
      bf16x8 vf1 = *(const bf16x8*)(Vts + (n * 16 + l16) * 72 + 32 + quad * 8);
      o[n] = __builtin_amdgcn_mfma_f32_16x16x32_bf16(pf[0], vf0, o[n], 0, 0, 0);
      o[n] = __builtin_amdgcn_mfma_f32_16x16x32_bf16(pf[1], vf1, o[n], 0, 0, 0);
    }
    bf16x8 v50 = *(const bf16x8*)(Vts + (64 + l16) * 72 + quad * 8);
    bf16x8 v51 = *(const bf16x8*)(Vts + (64 + l16) * 72 + 32 + quad * 8);
    o5 = __builtin_amdgcn_mfma_f32_16x16x32_bf16(pf[0], v50, o5, 0, 0, 0);
    o5 = __builtin_amdgcn_mfma_f32_16x16x32_bf16(pf[1], v51, o5, 0, 0, 0);
  }

  // normalize + store to attn [8192][768] bf16, col = h*64 + d.
  // row sum for row quad*4+r lives in lane quad*16 (col 0) of o5.
  for (int r = 0; r < 4; r++) {
    float s = __shfl(o5[r], quad << 4);
    float inv = 1.0f / s;
    int qrow = q_base + quad * 4 + r;
    size_t rowoff = (size_t)(b * SEQ + qrow) * EDIM + h * DH;
    for (int n = 0; n < 4; n++)
      attn[rowoff + n * 16 + l16] = f2bf(o[n][r] * inv);
  }
}

// ---------------- GEMM 3: output projection ----------------
__global__ __launch_bounds__(256, 3) void gemm_out(
    const u16* __restrict__ A, const u16* __restrict__ Bt,
    const float* __restrict__ bo, float* __restrict__ out) {
  __shared__ u16 As[128 * 64];
  __shared__ u16 Bs[128 * 64];
  int tid = threadIdx.x;
  int wv = tid >> 6, lane = tid & 63, quad = lane >> 4, l16 = lane & 15;
  int wm = (wv & 1) * 64, wn = (wv >> 1) * 64;
  int m0 = blockIdx.x * 128, n0 = blockIdx.y * 128;
  f32x4 acc[4][4] = {};
  gemm_core64(A, Bt, As, Bs, m0, n0, tid, acc);

  for (int i = 0; i < 4; i++) {
    int row0 = m0 + wm + i * 16 + quad * 4;
    for (int j = 0; j < 4; j++) {
      int n = n0 + wn + j * 16 + l16;
      float bias = bo[n];
      for (int r = 0; r < 4; r++)
        out[(size_t)(row0 + r) * EDIM + n] = acc[i][j][r] + bias;
    }
  }
}

// ---------------- launch ----------------
extern "C" void kernel_launch(void* const* d_in, const int* in_sizes, int n_in,
                              void* d_out, int out_size, void* d_ws, size_t ws_size,
                              hipStream_t stream) {
  const float* x  = (const float*)d_in[0];
  const float* Wq = (const float*)d_in[1];
  const float* bq = (const float*)d_in[2];
  const float* Wk = (const float*)d_in[3];
  const float* bk = (const float*)d_in[4];
  const float* Wv = (const float*)d_in[5];
  const float* bv = (const float*)d_in[6];
  const float* Wo = (const float*)d_in[7];
  const float* bo = (const float*)d_in[8];
  float* out = (float*)d_out;
  char* ws = (char*)d_ws;

  u16* Xb   = (u16*)(ws);                      // 8192*768*2    = 12,582,912
  u16* Wt   = (u16*)(ws + 12582912);           // 2304*768*2    =  3,538,944
  u16* Wot  = (u16*)(ws + 16121856);           // 768*768*2     =  1,179,648
  u16* qkv  = (u16*)(ws + 17301504);           // 3*96*1024*64*2= 37,748,736
  u16* attn = (u16*)(ws + 55050240);           // 8192*768*2    = 12,582,912

  cvt_x<<<6144, 256, 0, stream>>>(x, Xb, MROWS * EDIM);
  pack_w<<<576, 256, 0, stream>>>(Wq, Wk, Wv, Wo, Wt, Wot);
  gemm_qkv<<<dim3(64, 18), 256, 0, stream>>>(Xb, Wt, bq, bk, bv, qkv);
  attn_kernel<<<dim3(96, 16), 256, 0, stream>>>(qkv, attn);
  gemm_out<<<dim3(64, 6), 256, 0, stream>>>(attn, Wot, bo, out);
}